// Round 6
// baseline (76.421 us; speedup 1.0000x reference)
//
#include <hip/hip_runtime.h>

#define NT 256          // threads per block (4 waves)
#define NSTEP 50        // trajectory length (init + 49 RK4 steps)

__device__ __forceinline__ void lorenz(float x, float y, float z,
                                       float S, float R, float Bb,
                                       float c0, float c1, float c2,
                                       float& dx, float& dy, float& dz) {
    dx = S * (y - x) + c0;
    dy = x * (R - z) - y + c1;
    dz = x * y - Bb * z + c2;
}

// fast tanh via hardware v_exp_f32 + v_rcp_f32; saturates correctly at +/-inf
__device__ __forceinline__ float tanh_fast(float x) {
    float e = __expf(2.0f * x);
    float r = __builtin_amdgcn_rcpf(e + 1.0f);
    return __builtin_fmaf(-2.0f, r, 1.0f);
}
__device__ __forceinline__ float sigmoid_fast(float x) {
    float e = __expf(-x);
    return __builtin_amdgcn_rcpf(1.0f + e);
}

__device__ __forceinline__ void st2(float* p, float a, float b) {
    float2 v; v.x = a; v.y = b;
    *(float2*)p = v;          // global_store_dwordx2, 8B-aligned by layout
}

__global__ __launch_bounds__(NT) void chaotic_embed_kernel(
    const float* __restrict__ features,
    const float* __restrict__ W1,  const float* __restrict__ b1,
    const float* __restrict__ W2,  const float* __restrict__ b2,
    const float* __restrict__ Wc1, const float* __restrict__ bc1,
    const float* __restrict__ Wc2, const float* __restrict__ bc2,
    const float* __restrict__ Wp1, const float* __restrict__ bp1,
    const float* __restrict__ Wp2, const float* __restrict__ bp2,
    float* __restrict__ out)
{
    const long p = (long)blockIdx.x * NT + threadIdx.x;

    // coalesced 16B feature load
    const float4 f4 = ((const float4*)features)[p];
    const float fv[4] = {f4.x, f4.y, f4.z, f4.w};

    // ---- MLPs. All weight indices are compile-time -> uniform scalar loads
    // (s_load, SGPR operands); no LDS, no barrier needed.

    // init net: tanh(tanh(f@W1+b1)@W2+b2)*2
    float h1[16];
    #pragma unroll
    for (int j = 0; j < 16; ++j) {
        float a = b1[j];
        #pragma unroll
        for (int i = 0; i < 4; ++i) a = __builtin_fmaf(fv[i], W1[i * 16 + j], a);
        h1[j] = tanh_fast(a);
    }
    float init[3];
    #pragma unroll
    for (int c = 0; c < 3; ++c) {
        float a = b2[c];
        #pragma unroll
        for (int j = 0; j < 16; ++j) a = __builtin_fmaf(h1[j], W2[j * 3 + c], a);
        init[c] = 2.0f * tanh_fast(a);
    }

    // coupling net: tanh(tanh(f@Wc1+bc1)@Wc2+bc2)
    float hc[8];
    #pragma unroll
    for (int j = 0; j < 8; ++j) {
        float a = bc1[j];
        #pragma unroll
        for (int i = 0; i < 4; ++i) a = __builtin_fmaf(fv[i], Wc1[i * 8 + j], a);
        hc[j] = tanh_fast(a);
    }
    float coup[3];
    #pragma unroll
    for (int c = 0; c < 3; ++c) {
        float a = bc2[c];
        #pragma unroll
        for (int j = 0; j < 8; ++j) a = __builtin_fmaf(hc[j], Wc2[j * 3 + c], a);
        coup[c] = tanh_fast(a);
    }

    // param net: sigmoid(relu(f@Wp1+bp1)@Wp2+bp2)
    float hp[8];
    #pragma unroll
    for (int j = 0; j < 8; ++j) {
        float a = bp1[j];
        #pragma unroll
        for (int i = 0; i < 4; ++i) a = __builtin_fmaf(fv[i], Wp1[i * 8 + j], a);
        hp[j] = fmaxf(a, 0.0f);
    }
    float sc[3];
    #pragma unroll
    for (int c = 0; c < 3; ++c) {
        float a = bp2[c];
        #pragma unroll
        for (int j = 0; j < 8; ++j) a = __builtin_fmaf(hp[j], Wp2[j * 3 + c], a);
        sc[c] = sigmoid_fast(a);
    }
    const float S  = 10.0f * (0.5f + sc[0]);
    const float R  = 28.0f * (0.5f + sc[1]);
    const float Bb = (8.0f / 3.0f) * (0.5f + sc[2]);

    const float c0 = coup[0], c1 = coup[1], c2 = coup[2];
    const float H = 0.01f, HH = 0.5f * 0.01f, H6 = 0.01f / 6.0f;

    float sx = init[0], sy = init[1], sz = init[2];

    auto step = [&]() {
        float k1x, k1y, k1z, k2x, k2y, k2z, k3x, k3y, k3z, k4x, k4y, k4z;
        lorenz(sx, sy, sz, S, R, Bb, c0, c1, c2, k1x, k1y, k1z);
        lorenz(sx + HH * k1x, sy + HH * k1y, sz + HH * k1z,
               S, R, Bb, c0, c1, c2, k2x, k2y, k2z);
        lorenz(sx + HH * k2x, sy + HH * k2y, sz + HH * k2z,
               S, R, Bb, c0, c1, c2, k3x, k3y, k3z);
        lorenz(sx + H * k3x, sy + H * k3y, sz + H * k3z,
               S, R, Bb, c0, c1, c2, k4x, k4y, k4z);
        sx += H6 * (k1x + 2.0f * k2x + 2.0f * k3x + k4x);
        sy += H6 * (k1y + 2.0f * k2y + 2.0f * k3y + k4y);
        sz += H6 * (k1z + 2.0f * k2z + 2.0f * k3z + k4z);
    };

    float* __restrict__ row = out + p * (3 * NSTEP);   // dword offset even -> 8B aligned

    // ---- group 0: entries 0..3 (init + 3 steps), 12 floats -> 6x float2
    {
        const float a0 = sx, a1 = sy, a2 = sz;
        step(); const float a3 = sx, a4 = sy, a5 = sz;
        step(); const float a6 = sx, a7 = sy, a8 = sz;
        step(); const float a9 = sx, a10 = sy, a11 = sz;
        st2(row + 0,  a0,  a1);  st2(row + 2,  a2,  a3);
        st2(row + 4,  a4,  a5);  st2(row + 6,  a6,  a7);
        st2(row + 8,  a8,  a9);  st2(row + 10, a10, a11);
    }

    // ---- groups 1..11: 4 steps each, entries 4g..4g+3
    for (int g = 1; g < 12; ++g) {
        step(); const float a0 = sx, a1 = sy, a2 = sz;
        step(); const float a3 = sx, a4 = sy, a5 = sz;
        step(); const float a6 = sx, a7 = sy, a8 = sz;
        step(); const float a9 = sx, a10 = sy, a11 = sz;
        float* q = row + 12 * g;
        st2(q + 0,  a0,  a1);  st2(q + 2,  a2,  a3);
        st2(q + 4,  a4,  a5);  st2(q + 6,  a6,  a7);
        st2(q + 8,  a8,  a9);  st2(q + 10, a10, a11);
    }

    // ---- tail: entries 48, 49
    {
        step(); const float a0 = sx, a1 = sy, a2 = sz;
        step(); const float a3 = sx, a4 = sy, a5 = sz;
        float* q = row + 144;
        st2(q + 0, a0, a1);  st2(q + 2, a2, a3);  st2(q + 4, a4, a5);
    }
}

extern "C" void kernel_launch(void* const* d_in, const int* in_sizes, int n_in,
                              void* d_out, int out_size, void* d_ws, size_t ws_size,
                              hipStream_t stream) {
    const float* features = (const float*)d_in[0];
    const float* W1  = (const float*)d_in[1];
    const float* b1  = (const float*)d_in[2];
    const float* W2  = (const float*)d_in[3];
    const float* b2  = (const float*)d_in[4];
    const float* Wc1 = (const float*)d_in[5];
    const float* bc1 = (const float*)d_in[6];
    const float* Wc2 = (const float*)d_in[7];
    const float* bc2 = (const float*)d_in[8];
    const float* Wp1 = (const float*)d_in[9];
    const float* bp1 = (const float*)d_in[10];
    const float* Wp2 = (const float*)d_in[11];
    const float* bp2 = (const float*)d_in[12];
    float* out = (float*)d_out;

    const int B = in_sizes[0] / 4;          // 262144
    const int grid = B / NT;                // 1024 blocks

    chaotic_embed_kernel<<<grid, NT, 0, stream>>>(
        features, W1, b1, W2, b2, Wc1, bc1, Wc2, bc2,
        Wp1, bp1, Wp2, bp2, out);
}

// Round 7
// 44.067 us; speedup vs baseline: 1.7342x; 1.7342x over previous
//
#include <hip/hip_runtime.h>

#define NT 256            // threads per block (4 waves)
#define NSTEP 50          // trajectory length
#define PSTR 17           // LDS dwords per particle per buffer (15 used + 2)
#define BUFW (64 * PSTR)  // dwords per buffer per wave

__device__ __forceinline__ void lorenz(float x, float y, float z,
                                       float S, float R, float Bb,
                                       float c0, float c1, float c2,
                                       float& dx, float& dy, float& dz) {
    dx = S * (y - x) + c0;
    dy = x * (R - z) - y + c1;
    dz = x * y - Bb * z + c2;
}

// pack two f32 -> two bf16 (round-half-up) in one dword; lo in low half
__device__ __forceinline__ unsigned int bpack(float lo, float hi) {
    unsigned int a = (__builtin_bit_cast(unsigned int, lo) + 0x8000u) >> 16;
    unsigned int b = (__builtin_bit_cast(unsigned int, hi) + 0x8000u) & 0xFFFF0000u;
    return a | b;
}
__device__ __forceinline__ float bunpack_lo(unsigned int w) {
    return __builtin_bit_cast(float, w << 16);
}
__device__ __forceinline__ float bunpack_hi(unsigned int w) {
    return __builtin_bit_cast(float, w & 0xFFFF0000u);
}

// fast tanh / sigmoid via hardware v_exp_f32 + v_rcp_f32
__device__ __forceinline__ float tanh_fast(float x) {
    float e = __expf(2.0f * x);
    float r = __builtin_amdgcn_rcpf(e + 1.0f);
    return __builtin_fmaf(-2.0f, r, 1.0f);
}
__device__ __forceinline__ float sigmoid_fast(float x) {
    float e = __expf(-x);
    return __builtin_amdgcn_rcpf(1.0f + e);
}

// one cooperative flush iteration: 64 lanes cover dwords [64k, 64k+64) of a
// chunk image (15 packed dwords per particle); e0dw = chunk f32 base offset.
__device__ __forceinline__ void flushIter(const unsigned int* __restrict__ fb,
                                          float* __restrict__ outW,
                                          int lane, int e0dw, int k) {
    const int i  = 64 * k + lane;          // 0..959
    const int pp = i / 15;                 // const divisor -> magic mul
    const int j  = i - pp * 15;
    const unsigned int v = fb[pp * PSTR + j];
    float2 o;
    o.x = bunpack_lo(v);
    o.y = bunpack_hi(v);
    *(float2*)(outW + pp * 150 + e0dw + 2 * j) = o;   // 8B-aligned
}

__global__ __launch_bounds__(NT) void chaotic_embed_kernel(
    const float* __restrict__ features,
    const float* __restrict__ W1,  const float* __restrict__ b1,
    const float* __restrict__ W2,  const float* __restrict__ b2,
    const float* __restrict__ Wc1, const float* __restrict__ bc1,
    const float* __restrict__ Wc2, const float* __restrict__ bc2,
    const float* __restrict__ Wp1, const float* __restrict__ bp1,
    const float* __restrict__ Wp2, const float* __restrict__ bp2,
    float* __restrict__ out)
{
    __shared__ unsigned int stage[4 * 2 * BUFW];   // per-wave double buffer

    const int tid  = threadIdx.x;
    const int wv   = tid >> 6;
    const int lane = tid & 63;

    const long p = (long)blockIdx.x * NT + tid;

    // coalesced 16B feature load
    const float4 f4 = ((const float4*)features)[p];
    const float fv[4] = {f4.x, f4.y, f4.z, f4.w};

    // ---- MLPs: compile-time weight indices -> uniform s_load, SGPR operands
    float h1[16];
    #pragma unroll
    for (int j = 0; j < 16; ++j) {
        float a = b1[j];
        #pragma unroll
        for (int i = 0; i < 4; ++i) a = __builtin_fmaf(fv[i], W1[i * 16 + j], a);
        h1[j] = tanh_fast(a);
    }
    float init[3];
    #pragma unroll
    for (int c = 0; c < 3; ++c) {
        float a = b2[c];
        #pragma unroll
        for (int j = 0; j < 16; ++j) a = __builtin_fmaf(h1[j], W2[j * 3 + c], a);
        init[c] = 2.0f * tanh_fast(a);
    }
    float hc[8];
    #pragma unroll
    for (int j = 0; j < 8; ++j) {
        float a = bc1[j];
        #pragma unroll
        for (int i = 0; i < 4; ++i) a = __builtin_fmaf(fv[i], Wc1[i * 8 + j], a);
        hc[j] = tanh_fast(a);
    }
    float coup[3];
    #pragma unroll
    for (int c = 0; c < 3; ++c) {
        float a = bc2[c];
        #pragma unroll
        for (int j = 0; j < 8; ++j) a = __builtin_fmaf(hc[j], Wc2[j * 3 + c], a);
        coup[c] = tanh_fast(a);
    }
    float hp[8];
    #pragma unroll
    for (int j = 0; j < 8; ++j) {
        float a = bp1[j];
        #pragma unroll
        for (int i = 0; i < 4; ++i) a = __builtin_fmaf(fv[i], Wp1[i * 8 + j], a);
        hp[j] = fmaxf(a, 0.0f);
    }
    float sc[3];
    #pragma unroll
    for (int c = 0; c < 3; ++c) {
        float a = bp2[c];
        #pragma unroll
        for (int j = 0; j < 8; ++j) a = __builtin_fmaf(hp[j], Wp2[j * 3 + c], a);
        sc[c] = sigmoid_fast(a);
    }
    const float S  = 10.0f * (0.5f + sc[0]);
    const float R  = 28.0f * (0.5f + sc[1]);
    const float Bb = (8.0f / 3.0f) * (0.5f + sc[2]);

    const float c0 = coup[0], c1 = coup[1], c2 = coup[2];
    const float H = 0.01f, HH = 0.5f * 0.01f, H6 = 0.01f / 6.0f;

    float sx = init[0], sy = init[1], sz = init[2];
    float px, py, pz;

    auto step = [&]() {
        float k1x, k1y, k1z, k2x, k2y, k2z, k3x, k3y, k3z, k4x, k4y, k4z;
        lorenz(sx, sy, sz, S, R, Bb, c0, c1, c2, k1x, k1y, k1z);
        lorenz(sx + HH * k1x, sy + HH * k1y, sz + HH * k1z,
               S, R, Bb, c0, c1, c2, k2x, k2y, k2z);
        lorenz(sx + HH * k2x, sy + HH * k2y, sz + HH * k2z,
               S, R, Bb, c0, c1, c2, k3x, k3y, k3z);
        lorenz(sx + H * k3x, sy + H * k3y, sz + H * k3z,
               S, R, Bb, c0, c1, c2, k4x, k4y, k4z);
        sx += H6 * (k1x + 2.0f * k2x + 2.0f * k3x + k4x);
        sy += H6 * (k1y + 2.0f * k2y + 2.0f * k3y + k4y);
        sz += H6 * (k1z + 2.0f * k2z + 2.0f * k3z + k4z);
    };

    unsigned int* wbase = stage + wv * (2 * BUFW);
    float* __restrict__ outW =
        out + ((long)blockIdx.x * NT + (long)wv * 64) * (3 * NSTEP);

    // ---- 5 chunks of 10 entries; compute chunk c while trickle-flushing c-1.
    // Per 2 RK4 steps: pack 3 dwords into write-buf + 3 flush iters of prev.
    #pragma unroll
    for (int c = 0; c < 5; ++c) {
        unsigned int* wb = wbase + (c & 1) * BUFW + lane * PSTR; // stride 17
        const unsigned int* fb = wbase + ((c & 1) ^ 1) * BUFW;
        const int e0dw = (c - 1) * 30;
        int u = 0;
        #pragma unroll
        for (int g = 0; g < 5; ++g) {
            // even step (skipped for the very first: entry 0 = init)
            if (c > 0 || g > 0) { step(); }
            px = sx; py = sy; pz = sz;
            step();                           // odd step
            wb[u + 0] = bpack(px, py);        // entries (even, odd)
            wb[u + 1] = bpack(pz, sx);
            wb[u + 2] = bpack(sy, sz);
            u += 3;
            if (c > 0) {                      // 3 flush iters of chunk c-1
                flushIter(fb, outW, lane, e0dw, 3 * g + 0);
                flushIter(fb, outW, lane, e0dw, 3 * g + 1);
                flushIter(fb, outW, lane, e0dw, 3 * g + 2);
            }
        }
    }

    // ---- final flush: chunk 4 (entries 40..49) from buf 0
    {
        const unsigned int* fb = wbase + 0 * BUFW;   // (4 & 1) == 0
        #pragma unroll
        for (int k = 0; k < 15; ++k)
            flushIter(fb, outW, lane, 120, k);
    }
}

extern "C" void kernel_launch(void* const* d_in, const int* in_sizes, int n_in,
                              void* d_out, int out_size, void* d_ws, size_t ws_size,
                              hipStream_t stream) {
    const float* features = (const float*)d_in[0];
    const float* W1  = (const float*)d_in[1];
    const float* b1  = (const float*)d_in[2];
    const float* W2  = (const float*)d_in[3];
    const float* b2  = (const float*)d_in[4];
    const float* Wc1 = (const float*)d_in[5];
    const float* bc1 = (const float*)d_in[6];
    const float* Wc2 = (const float*)d_in[7];
    const float* bc2 = (const float*)d_in[8];
    const float* Wp1 = (const float*)d_in[9];
    const float* bp1 = (const float*)d_in[10];
    const float* Wp2 = (const float*)d_in[11];
    const float* bp2 = (const float*)d_in[12];
    float* out = (float*)d_out;

    const int B = in_sizes[0] / 4;          // 262144
    const int grid = B / NT;                // 1024 blocks, 4/CU, all resident

    chaotic_embed_kernel<<<grid, NT, 0, stream>>>(
        features, W1, b1, W2, b2, Wc1, bc1, Wc2, bc2,
        Wp1, bp1, Wp2, bp2, out);
}